// Round 9
// baseline (1060.165 us; speedup 1.0000x reference)
//
#include <hip/hip_runtime.h>
#include <math.h>

#define GRID_N 5
#define LOG2E 1.4426950408889634f
#define EXP2F __builtin_amdgcn_exp2f
#define BATCH 2048

// tanh + bin(1..5) packed into low 3 mantissa bits of tanh(v) (rel perturb <= 2^-21)
__device__ __forceinline__ unsigned pack_xn(float v) {
    float ex = EXP2F(2.0f * LOG2E * v);
    float t  = 1.0f - 2.0f / (ex + 1.0f);       // tanh, NaN-safe
    int k = (int)((t + 1.0f) * 2.0f) + 1;       // #{grid g <= t}, t in [-1,1]
    k = k > 5 ? 5 : k;
    return (__float_as_uint(t) & ~7u) | (unsigned)k;
}

// Per-(i,o) bin tables:  K = -s*log2e
//   A[k] = sum_{g_idx < k} w_g * 2^{-K*g},  B[k] = sum_{g_idx >= k} w_g * 2^{+K*g}
// T[i][k][o][2] = {A,B} (k=0..5);  Kt[i][o] = K
__device__ __forceinline__ void prep_one(const float* __restrict__ w,
                                         const float* __restrict__ s,
                                         float* __restrict__ T, float* __restrict__ Kt,
                                         int O, int I, int idx) {
    int o = idx / I, i = idx % I;               // w,s are [O][I(][G)]
    float K = -s[idx] * LOG2E;
    const float gv[5] = {-1.f, -0.5f, 0.f, 0.5f, 1.f};
    float A[6], B[6];
    A[0] = 0.f; B[5] = 0.f;
#pragma unroll
    for (int g = 0; g < 5; g++)
        A[g + 1] = A[g] + w[idx * GRID_N + g] * EXP2F(-K * gv[g]);
#pragma unroll
    for (int g = 4; g >= 0; g--)
        B[g] = B[g + 1] + w[idx * GRID_N + g] * EXP2F(K * gv[g]);
#pragma unroll
    for (int k = 0; k < 6; k++) {
        T[((i * 6 + k) * O + o) * 2 + 0] = A[k];
        T[((i * 6 + k) * O + o) * 2 + 1] = B[k];
    }
    Kt[i * O + o] = K;
}

__global__ __launch_bounds__(256) void prep_all(
    const float* __restrict__ w1, const float* __restrict__ s1, float* T1, float* K1,
    const float* __restrict__ w2, const float* __restrict__ s2, float* T2, float* K2,
    const float* __restrict__ w3, const float* __restrict__ s3, float* T3, float* K3) {
    int idx = blockIdx.x * 256 + threadIdx.x;
    if (idx < 32768)       prep_one(w1, s1, T1, K1, 256, 128, idx);
    else if (idx < 65536)  prep_one(w2, s2, T2, K2, 128, 256, idx - 32768);
    else if (idx < 73728)  prep_one(w3, s3, T3, K3,  64, 128, idx - 65536);
}

// ================= LDS double-buffered layer =================
// Tile = 8 i's: AB slice [8i][6k][64o]{A,B} = 24 KB + K [8i][64o] = 2 KB.
// Double-buffered: 52 KB LDS -> 3 blocks/CU. One barrier per tile:
//   barrier; LOADG(t+1)->regs; COMPUTE(t) from LDS; WRITEL(t+1)->other buffer.
// Gathers go on the LDS pipe (ds_read_b64, 2-way alias = free); VMEM pipe only
// streams the table linearly. bin packed in xn => 1 readlane/term.
#define ABH 24576
#define KB0 49152
#define KH  2048

#define LOADG(t)                                                               \
    {                                                                          \
        _Pragma("unroll")                                                      \
        for (int n = 0; n < 6; n++) {                                          \
            int e = n * 256 + tid;                                             \
            sreg[n] = *(const float4*)(Tb + (size_t)((t) * 48 + (e >> 5)) * (OUT * 8) \
                                        + (oc << 9) + ((e & 31) << 4));        \
        }                                                                      \
        kreg = *(const float2*)(Kb + (size_t)((t) * 8 + (tid >> 5)) * (OUT * 4) \
                                 + (oc << 8) + ((tid & 31) << 3));             \
    }

#define WRITEL(p)                                                              \
    {                                                                          \
        _Pragma("unroll")                                                      \
        for (int n = 0; n < 6; n++)                                            \
            *(float4*)(lds + (p) * ABH + ((n * 256 + tid) << 4)) = sreg[n];    \
        *(float2*)(lds + KB0 + (p) * KH + (tid << 3)) = kreg;                  \
    }

#define COMPUTE(p, c, tt)                                                      \
    _Pragma("unroll")                                                          \
    for (int il = 0; il < 8; il++) {                                           \
        float Kv = *(const float*)(lds + KB0 + (p) * KH + il * 256 + lane4);   \
        _Pragma("unroll")                                                      \
        for (int j = 0; j < BPT; j++) {                                        \
            unsigned raw = (unsigned)__builtin_amdgcn_readlane((int)xp[j][c], (tt) * 8 + il); \
            float2 ab = *(const float2*)(lds + (p) * ABH + ((il * 6 + (int)(raw & 7u)) << 9) + lane8); \
            float xs = __uint_as_float(raw);                                   \
            float targ = Kv * xs;                                              \
            acc[j] += ab.x * EXP2F(targ) + ab.y * EXP2F(-targ);                \
        }                                                                      \
    }

template<int IN, int OUT, int OCH, int BPT>
__global__ __launch_bounds__(256, 3) void kan_lds(
    const float* __restrict__ xin,   // [B][IN] pre-tanh (relu'd by producer)
    const char*  __restrict__ Tb,    // [IN][6][OUT]{A,B} f32 bytes
    const char*  __restrict__ Kb,    // [IN][OUT] f32 bytes
    float* __restrict__ outp)        // [B][OUT], relu applied
{
    constexpr int TILES = IN / 8;
    constexpr int CH    = IN / 64;
    __shared__ float4 ldsbuf[(2 * ABH + 2 * KH) / 16];
    char* lds = (char*)ldsbuf;

    const int tid  = threadIdx.x;
    const int lane = tid & 63;
    const int w    = tid >> 6;
    const int oc   = blockIdx.x % OCH;
    const int bb   = blockIdx.x / OCH;
    const int o    = (oc << 6) | lane;
    const int bw   = bb * (4 * BPT) + w * BPT;
    const int lane4 = lane << 2, lane8 = lane << 3;

    // per-lane packed xn: lane l holds i = c*64 + l for each of BPT rows
    unsigned xp[BPT][CH];
#pragma unroll
    for (int j = 0; j < BPT; j++)
#pragma unroll
        for (int c = 0; c < CH; c++)
            xp[j][c] = pack_xn(xin[(bw + j) * IN + (c << 6) + lane]);

    float acc[BPT];
#pragma unroll
    for (int j = 0; j < BPT; j++) acc[j] = 0.f;

    float4 sreg[6];
    float2 kreg;

    LOADG(0);
    WRITEL(0);
#pragma unroll
    for (int c = 0; c < CH; c++) {
#pragma unroll
        for (int tt = 0; tt < 8; tt++) {
            const int t = c * 8 + tt;            // unrolled -> compile-time
            __syncthreads();                     // tile t ready in buf t&1
            if (t + 1 < TILES) LOADG(t + 1);     // stream next tile -> regs
            COMPUTE(t & 1, c, tt);
            if (t + 1 < TILES) WRITEL((t + 1) & 1);
        }
    }

#pragma unroll
    for (int j = 0; j < BPT; j++)
        outp[(bw + j) * OUT + o] = fmaxf(acc[j], 0.f);
}

// ================= small L3 (R7 pipelined gather path) =================
#define LOADB(lb, AB, KV)                                                      \
    _Pragma("unroll")                                                          \
    for (int u = 0; u < 8; u++) {                                              \
        const int l  = (lb) * 8 + u;                                           \
        const int gi = hbase + c * 64 + l;                                     \
        KV[u] = Kt[gi * OUT + o];                                              \
        _Pragma("unroll")                                                      \
        for (int j = 0; j < BPT; j++) {                                        \
            unsigned os = (unsigned)__builtin_amdgcn_readlane((int)off[j][c], l); \
            AB[j][u] = *(const float2*)(Tb + (os + o8));                       \
        }                                                                      \
    }

#define COMPB(lb, AB, KV)                                                      \
    _Pragma("unroll")                                                          \
    for (int u = 0; u < 8; u++) {                                              \
        const int l = (lb) * 8 + u;                                            \
        _Pragma("unroll")                                                      \
        for (int j = 0; j < BPT; j++) {                                        \
            float xs = __int_as_float(__builtin_amdgcn_readlane(__float_as_int(xv[j][c]), l)); \
            float t  = KV[u] * xs;                                             \
            acc[j] += AB[j][u].x * EXP2F(t) + AB[j][u].y * EXP2F(-t);          \
        }                                                                      \
    }

template<int LEN, int OUT, int OCH, int BPT, int HALVES, int EPI>
__global__ __launch_bounds__(256) __attribute__((amdgpu_waves_per_eu(4, 4)))
void kan_pipe(const float* __restrict__ xin,
              const char*  __restrict__ Tb,
              const float* __restrict__ Kt,
              float* __restrict__ outp)
{
    constexpr int CH   = LEN / 64;
    constexpr int NBG  = BATCH / BPT;
    constexpr int XSTR = LEN * HALVES;
    constexpr unsigned ROWB = OUT * 8;

    const int lane = threadIdx.x & 63;
    const int wid  = (blockIdx.x << 2) | (threadIdx.x >> 6);
    const int oc   = wid / (NBG * HALVES);
    const int rem  = wid % (NBG * HALVES);
    const int h    = rem / NBG;
    const int bg   = rem % NBG;
    const int o    = (oc << 6) | lane;
    const int b0   = bg * BPT;
    const int hbase = h * LEN;

    float    xv[BPT][CH];
    unsigned off[BPT][CH];
#pragma unroll
    for (int j = 0; j < BPT; j++)
#pragma unroll
        for (int c = 0; c < CH; c++) {
            const int gi = hbase + (c << 6) + lane;
            float v  = xin[(b0 + j) * XSTR + gi];
            float ex = EXP2F(2.0f * LOG2E * v);
            float t  = 1.0f - 2.0f / (ex + 1.0f);
            xv[j][c] = t;
            int k = (int)((t + 1.0f) * 2.0f) + 1;
            k = k > 5 ? 5 : k;
            off[j][c] = (unsigned)(gi * 6 + k) * ROWB;
        }

    float acc[BPT];
#pragma unroll
    for (int j = 0; j < BPT; j++) acc[j] = 0.f;

    const unsigned o8 = (unsigned)o * 8u;

#pragma unroll
    for (int c = 0; c < CH; c++) {
        float2 abA[BPT][8], abB[BPT][8];
        float  KvA[8], KvB[8];
        LOADB(0, abA, KvA);
#pragma unroll
        for (int p = 0; p < 3; p++) {
            LOADB(2 * p + 1, abB, KvB);
            COMPB(2 * p,     abA, KvA);
            LOADB(2 * p + 2, abA, KvA);
            COMPB(2 * p + 1, abB, KvB);
        }
        LOADB(7, abB, KvB);
        COMPB(6, abA, KvA);
        COMPB(7, abB, KvB);
    }

#pragma unroll
    for (int j = 0; j < BPT; j++) {
        float z = acc[j];
        if (EPI == 0) z = fmaxf(z, 0.f);
        outp[(h * BATCH + (b0 + j)) * OUT + o] = z;
    }
}

__global__ __launch_bounds__(256) void sigmoid_combine(
    const float* __restrict__ p, float* __restrict__ out, int n) {
    int e = blockIdx.x * 256 + threadIdx.x;
    if (e >= n) return;
    float z = p[e] + p[n + e];
    out[e] = 1.0f / (1.0f + EXP2F(-LOG2E * z));
}

extern "C" void kernel_launch(void* const* d_in, const int* in_sizes, int n_in,
                              void* d_out, int out_size, void* d_ws, size_t ws_size,
                              hipStream_t stream) {
    const float* x  = (const float*)d_in[0];
    const float* w1 = (const float*)d_in[1];
    const float* s1 = (const float*)d_in[2];
    const float* w2 = (const float*)d_in[3];
    const float* s2 = (const float*)d_in[4];
    const float* w3 = (const float*)d_in[5];
    const float* s3 = (const float*)d_in[6];
    float* out = (float*)d_out;

    float* ws  = (float*)d_ws;
    float* h1  = ws;                    // 2048*256   = 524288
    float* h2  = h1  + 524288;          // 2048*128   = 262144
    float* p3  = h2  + 262144;          // 2*2048*64  = 262144
    float* T1  = p3  + 262144;          // 393216
    float* K1  = T1  + 393216;          // 32768
    float* T2  = K1  + 32768;           // 393216
    float* K2  = T2  + 393216;          // 32768
    float* T3  = K2  + 32768;           // 98304
    float* K3  = T3  + 98304;           // 8192

    prep_all<<<288, 256, 0, stream>>>(w1, s1, T1, K1, w2, s2, T2, K2, w3, s3, T3, K3);

    // L1: 128 bb (BPT=4 -> 16 rows/block) x 4 oc = 512 blocks, 3/CU-resident
    kan_lds<128, 256, 4, 4><<<512, 256, 0, stream>>>(
        x, (const char*)T1, (const char*)K1, h1);
    // L2: 256 bb (BPT=2 -> 8 rows/block) x 2 oc = 512 blocks
    kan_lds<256, 128, 2, 2><<<512, 256, 0, stream>>>(
        h1, (const char*)T2, (const char*)K2, h2);
    // L3: LEN=64 (2 halves of 128), OUT=64 -> 2048 waves, 512 blocks; raw partials
    kan_pipe<64, 64, 1, 2, 2, 1><<<512, 256, 0, stream>>>(
        h2, (const char*)T3, K3, p3);
    // epilogue: sigmoid(p0+p1) -> out
    sigmoid_combine<<<512, 256, 0, stream>>>(p3, out, 131072);
}

// Round 10
// 123.788 us; speedup vs baseline: 8.5643x; 8.5643x over previous
//
#include <hip/hip_runtime.h>
#include <math.h>

#define GRID_N 5
#define LOG2E 1.4426950408889634f
#define EXP2F __builtin_amdgcn_exp2f
#define BATCH 2048

// Per-(i,o) bin tables:  K = -s*log2e
//   A[k] = sum_{g_idx < k} w_g * 2^{-K*g},  B[k] = sum_{g_idx >= k} w_g * 2^{+K*g}
// T[i][k][o][2] = {A,B} (k=0..5);  Kt[i][o] = K
__device__ __forceinline__ void prep_one(const float* __restrict__ w,
                                         const float* __restrict__ s,
                                         float* __restrict__ T, float* __restrict__ Kt,
                                         int O, int I, int idx) {
    int o = idx / I, i = idx % I;               // w,s are [O][I(][G)]
    float K = -s[idx] * LOG2E;
    const float gv[5] = {-1.f, -0.5f, 0.f, 0.5f, 1.f};
    float A[6], B[6];
    A[0] = 0.f; B[5] = 0.f;
#pragma unroll
    for (int g = 0; g < 5; g++)
        A[g + 1] = A[g] + w[idx * GRID_N + g] * EXP2F(-K * gv[g]);
#pragma unroll
    for (int g = 4; g >= 0; g--)
        B[g] = B[g + 1] + w[idx * GRID_N + g] * EXP2F(K * gv[g]);
#pragma unroll
    for (int k = 0; k < 6; k++) {
        T[((i * 6 + k) * O + o) * 2 + 0] = A[k];
        T[((i * 6 + k) * O + o) * 2 + 1] = B[k];
    }
    Kt[i * O + o] = K;
}

__global__ __launch_bounds__(256) void prep_all(
    const float* __restrict__ w1, const float* __restrict__ s1, float* T1, float* K1,
    const float* __restrict__ w2, const float* __restrict__ s2, float* T2, float* K2,
    const float* __restrict__ w3, const float* __restrict__ s3, float* T3, float* K3) {
    int idx = blockIdx.x * 256 + threadIdx.x;
    if (idx < 32768)       prep_one(w1, s1, T1, K1, 256, 128, idx);
    else if (idx < 65536)  prep_one(w2, s2, T2, K2, 128, 256, idx - 32768);
    else if (idx < 73728)  prep_one(w3, s3, T3, K3,  64, 128, idx - 65536);
}

// ---- phase-locked direct-gather KAN layer ----
// out[b,o] (+)= sum_{i in my half} A[i,bin,o]*2^{K*xn} + B[i,bin,o]*2^{-K*xn}
// Wave = 64 o's (lane=o) x BPT b-rows. Block = 4 waves, SAME o-chunk, 16 b-rows.
// __syncthreads() every 8 i's keeps waves phase-locked so the 8-i table window
// (26 KB) stays L1-resident: each (i,bin) row fetched from L2 once per block
// instead of once per wave-term (~4x L2-traffic cut vs R4).
// AB loads are wave-uniform-base (readlane -> SGPR) + lane*8 -> fully coalesced.
// XMODE: 0 = xin raw floats; 1 = relu(p0+p1) partial-pair combine (L3)
// EPI:   0 = relu f32; 1 = raw partial f32
template<int LEN, int OUT, int OCH, int BPT, int HALVES, int EPI, int XMODE>
__global__ __launch_bounds__(256) void kan_sync(
    const float* __restrict__ xin,   // XMODE0: [B][LEN*HALVES]; XMODE1: [2][B][LEN*HALVES]
    const char*  __restrict__ Tb,    // [LEN*HALVES][6][OUT]{A,B} f32 bytes
    const float* __restrict__ Kt,    // [LEN*HALVES][OUT]
    float* __restrict__ outp)        // [HALVES][B][OUT]
{
    constexpr int CH   = LEN / 64;
    constexpr int ROWS = 4 * BPT;              // b-rows per block
    constexpr int XSTR = LEN * HALVES;         // input row stride
    constexpr unsigned ROWB = OUT * 8;

    const int tid  = threadIdx.x;
    const int lane = tid & 63;
    const int w    = tid >> 6;
    const int h    = (HALVES > 1) ? (blockIdx.x % HALVES) : 0;
    const int q    = blockIdx.x / HALVES;
    const int oc   = q % OCH;
    const int bb   = q / OCH;
    const int o    = (oc << 6) | lane;
    const int b0   = bb * ROWS + w * BPT;
    const int hbase = h * LEN;

    // stage: per-lane tanh + table byte-offset (lane l -> i = hbase + c*64 + l)
    float    xv[BPT][CH];
    unsigned off[BPT][CH];
#pragma unroll
    for (int j = 0; j < BPT; j++)
#pragma unroll
        for (int c = 0; c < CH; c++) {
            const int gi = hbase + (c << 6) + lane;
            float v;
            if (XMODE == 0) {
                v = xin[(b0 + j) * XSTR + gi];
            } else {
                int e = (b0 + j) * XSTR + gi;
                v = fmaxf(xin[e] + xin[BATCH * XSTR + e], 0.f);
            }
            float ex = EXP2F(2.0f * LOG2E * v);
            float t  = 1.0f - 2.0f / (ex + 1.0f);       // tanh, NaN-safe
            xv[j][c] = t;
            int k = (int)((t + 1.0f) * 2.0f) + 1;       // #{g <= t}
            k = k > 5 ? 5 : k;
            off[j][c] = (unsigned)(gi * 6 + k) * ROWB;
        }

    float acc[BPT];
#pragma unroll
    for (int j = 0; j < BPT; j++) acc[j] = 0.f;

    const unsigned o8 = (unsigned)o * 8u;

#pragma unroll
    for (int c = 0; c < CH; c++) {
#pragma unroll 1
        for (int ph = 0; ph < 8; ph++) {       // 8 i's per phase
            __syncthreads();                   // phase-lock block's 4 waves
#pragma unroll
            for (int u = 0; u < 8; u++) {
                const int l  = (ph << 3) + u;
                const int gi = hbase + (c << 6) + l;
                float Kv = Kt[gi * OUT + o];
                float2 ab[BPT];
#pragma unroll
                for (int j = 0; j < BPT; j++) {
                    unsigned os = (unsigned)__builtin_amdgcn_readlane((int)off[j][c], l);
                    ab[j] = *(const float2*)(Tb + (os + o8));
                }
#pragma unroll
                for (int j = 0; j < BPT; j++) {
                    float xs = __int_as_float(__builtin_amdgcn_readlane(__float_as_int(xv[j][c]), l));
                    float t  = Kv * xs;
                    acc[j] += ab[j].x * EXP2F(t) + ab[j].y * EXP2F(-t);
                }
            }
        }
    }

#pragma unroll
    for (int j = 0; j < BPT; j++) {
        float z = acc[j];
        if (EPI == 0) z = fmaxf(z, 0.f);
        outp[(h * BATCH + (b0 + j)) * OUT + o] = z;
    }
}

// out[e] = sigmoid(p0[e] + p1[e])
__global__ __launch_bounds__(256) void sigmoid_combine(
    const float* __restrict__ p, float* __restrict__ out, int n) {
    int e = blockIdx.x * 256 + threadIdx.x;
    if (e >= n) return;
    float z = p[e] + p[n + e];
    out[e] = 1.0f / (1.0f + EXP2F(-LOG2E * z));
}

extern "C" void kernel_launch(void* const* d_in, const int* in_sizes, int n_in,
                              void* d_out, int out_size, void* d_ws, size_t ws_size,
                              hipStream_t stream) {
    const float* x  = (const float*)d_in[0];
    const float* w1 = (const float*)d_in[1];
    const float* s1 = (const float*)d_in[2];
    const float* w2 = (const float*)d_in[3];
    const float* s2 = (const float*)d_in[4];
    const float* w3 = (const float*)d_in[5];
    const float* s3 = (const float*)d_in[6];
    float* out = (float*)d_out;

    float* ws  = (float*)d_ws;
    float* h1  = ws;                    // 2048*256   = 524288
    float* p2  = h1  + 524288;          // 2*2048*128 = 524288
    float* p3  = p2  + 524288;          // 2*2048*64  = 262144
    float* T1  = p3  + 262144;          // 393216
    float* K1  = T1  + 393216;          // 32768
    float* T2  = K1  + 32768;           // 393216
    float* K2  = T2  + 393216;          // 32768
    float* T3  = K2  + 32768;           // 98304
    float* K3  = T3  + 98304;           // 8192

    prep_all<<<288, 256, 0, stream>>>(w1, s1, T1, K1, w2, s2, T2, K2, w3, s3, T3, K3);

    // L1: LEN=128, OUT=256, OCH=4, BPT=4 -> 128 bb x 4 oc = 512 blocks (2/CU)
    kan_sync<128, 256, 4, 4, 1, 0, 0><<<512, 256, 0, stream>>>(
        x, (const char*)T1, K1, h1);
    // L2: 256 i's as 2 halves; OUT=128, OCH=2, BPT=4 -> 128 x 2 x 2 = 512 blocks; raw partials
    kan_sync<128, 128, 2, 4, 2, 1, 0><<<512, 256, 0, stream>>>(
        h1, (const char*)T2, K2, p2);
    // L3: 128 i's as 2 halves; OUT=64, OCH=1, BPT=4, combine p2 inline -> 256 blocks; raw partials
    kan_sync<64, 64, 1, 4, 2, 1, 1><<<256, 256, 0, stream>>>(
        p2, (const char*)T3, K3, p3);
    // epilogue: sigmoid(p0+p1) -> out  (2048*64 = 131072 elems)
    sigmoid_combine<<<512, 256, 0, stream>>>(p3, out, 131072);
}

// Round 11
// 103.251 us; speedup vs baseline: 10.2679x; 1.1989x over previous
//
#include <hip/hip_runtime.h>
#include <math.h>

#define GRID_N 5
#define LOG2E 1.4426950408889634f
#define EXP2F __builtin_amdgcn_exp2f
#define BATCH 2048
#define SB()  __builtin_amdgcn_sched_barrier(0)

// Per-(i,o) bin tables:  K = -s*log2e
//   A[k] = sum_{g_idx < k} w_g * 2^{-K*g},  B[k] = sum_{g_idx >= k} w_g * 2^{+K*g}
// T[i][k][o][2] = {A,B} (k=0..5);  Kt[i][o] = K
__device__ __forceinline__ void prep_one(const float* __restrict__ w,
                                         const float* __restrict__ s,
                                         float* __restrict__ T, float* __restrict__ Kt,
                                         int O, int I, int idx) {
    int o = idx / I, i = idx % I;               // w,s are [O][I(][G)]
    float K = -s[idx] * LOG2E;
    const float gv[5] = {-1.f, -0.5f, 0.f, 0.5f, 1.f};
    float A[6], B[6];
    A[0] = 0.f; B[5] = 0.f;
#pragma unroll
    for (int g = 0; g < 5; g++)
        A[g + 1] = A[g] + w[idx * GRID_N + g] * EXP2F(-K * gv[g]);
#pragma unroll
    for (int g = 4; g >= 0; g--)
        B[g] = B[g + 1] + w[idx * GRID_N + g] * EXP2F(K * gv[g]);
#pragma unroll
    for (int k = 0; k < 6; k++) {
        T[((i * 6 + k) * O + o) * 2 + 0] = A[k];
        T[((i * 6 + k) * O + o) * 2 + 1] = B[k];
    }
    Kt[i * O + o] = K;
}

__global__ __launch_bounds__(256) void prep_all(
    const float* __restrict__ w1, const float* __restrict__ s1, float* T1, float* K1,
    const float* __restrict__ w2, const float* __restrict__ s2, float* T2, float* K2,
    const float* __restrict__ w3, const float* __restrict__ s3, float* T3, float* K3) {
    int idx = blockIdx.x * 256 + threadIdx.x;
    if (idx < 32768)       prep_one(w1, s1, T1, K1, 256, 128, idx);
    else if (idx < 65536)  prep_one(w2, s2, T2, K2, 128, 256, idx - 32768);
    else if (idx < 73728)  prep_one(w3, s3, T3, K3,  64, 128, idx - 65536);
}

// ---- sched_barrier-pinned software-pipelined KAN layer ----
// out[b,o] (+)= sum_{i in my half} A[i,bin,o]*2^{K*xn} + B[i,bin,o]*2^{-K*xn}
// Wave = 64 o's (lane=o) x BPT b-rows. Ping-pong batches of 8 i's; every
// LOADB/COMPB boundary is fenced with sched_barrier(0) so the scheduler CANNOT
// sink batch t+1's 24 loads below batch t's compute -> 24 loads stay in flight
// (forced ~110 VGPR), one L2 round-trip per 8-i batch hidden under 16 exp2.
#define LOADB(lb, AB, KV)                                                      \
    _Pragma("unroll")                                                          \
    for (int u = 0; u < 8; u++) {                                              \
        const int l  = (lb) * 8 + u;                                           \
        const int gi = hbase + c * 64 + l;                                     \
        KV[u] = Kt[gi * OUT + o];                                              \
        _Pragma("unroll")                                                      \
        for (int j = 0; j < BPT; j++) {                                        \
            unsigned os = (unsigned)__builtin_amdgcn_readlane((int)off[j][c], l); \
            AB[j][u] = *(const float2*)(Tb + (os + o8));                       \
        }                                                                      \
    }

#define COMPB(lb, AB, KV)                                                      \
    _Pragma("unroll")                                                          \
    for (int u = 0; u < 8; u++) {                                              \
        const int l = (lb) * 8 + u;                                            \
        _Pragma("unroll")                                                      \
        for (int j = 0; j < BPT; j++) {                                        \
            float xs = __int_as_float(__builtin_amdgcn_readlane(__float_as_int(xv[j][c]), l)); \
            float t  = KV[u] * xs;                                             \
            acc[j] += AB[j][u].x * EXP2F(t) + AB[j][u].y * EXP2F(-t);          \
        }                                                                      \
    }

template<int LEN, int OUT, int OCH, int BPT, int HALVES, int EPI>
__global__ __launch_bounds__(256) __attribute__((amdgpu_waves_per_eu(4, 4)))
void kan_pipe(const float* __restrict__ xin,   // [B][LEN*HALVES]
              const char*  __restrict__ Tb,    // [LEN*HALVES][6][OUT]{A,B} f32
              const float* __restrict__ Kt,    // [LEN*HALVES][OUT]
              float* __restrict__ outp)        // [HALVES][B][OUT]
{
    constexpr int CH   = LEN / 64;
    constexpr int NBG  = BATCH / BPT;
    constexpr int XSTR = LEN * HALVES;
    constexpr unsigned ROWB = OUT * 8;

    const int lane = threadIdx.x & 63;
    const int wid  = (blockIdx.x << 2) | (threadIdx.x >> 6);
    const int oc   = wid / (NBG * HALVES);
    const int rem  = wid % (NBG * HALVES);
    const int h    = rem / NBG;
    const int bg   = rem % NBG;
    const int o    = (oc << 6) | lane;
    const int b0   = bg * BPT;
    const int hbase = h * LEN;

    // stage: per-lane tanh + table byte-offset (lane l -> i = hbase + c*64 + l)
    float    xv[BPT][CH];
    unsigned off[BPT][CH];
#pragma unroll
    for (int j = 0; j < BPT; j++)
#pragma unroll
        for (int c = 0; c < CH; c++) {
            const int gi = hbase + (c << 6) + lane;
            float v  = xin[(b0 + j) * XSTR + gi];
            float ex = EXP2F(2.0f * LOG2E * v);
            float t  = 1.0f - 2.0f / (ex + 1.0f);       // tanh, NaN-safe
            xv[j][c] = t;
            int k = (int)((t + 1.0f) * 2.0f) + 1;       // #{g <= t}
            k = k > 5 ? 5 : k;
            off[j][c] = (unsigned)(gi * 6 + k) * ROWB;
        }

    float acc[BPT];
#pragma unroll
    for (int j = 0; j < BPT; j++) acc[j] = 0.f;

    const unsigned o8 = (unsigned)o * 8u;

#pragma unroll
    for (int c = 0; c < CH; c++) {
        float2 abA[BPT][8], abB[BPT][8];
        float  KvA[8], KvB[8];
        LOADB(0, abA, KvA); SB();
#pragma unroll
        for (int p = 0; p < 3; p++) {
            LOADB(2 * p + 1, abB, KvB); SB();
            COMPB(2 * p,     abA, KvA); SB();
            LOADB(2 * p + 2, abA, KvA); SB();
            COMPB(2 * p + 1, abB, KvB); SB();
        }
        LOADB(7, abB, KvB); SB();
        COMPB(6, abA, KvA); SB();
        COMPB(7, abB, KvB); SB();
    }

#pragma unroll
    for (int j = 0; j < BPT; j++) {
        float z = acc[j];
        if (EPI == 0) z = fmaxf(z, 0.f);
        outp[(h * BATCH + (b0 + j)) * OUT + o] = z;
    }
}

// out[e] = sigmoid(p0[e] + p1[e])
__global__ __launch_bounds__(256) void sigmoid_combine(
    const float* __restrict__ p, float* __restrict__ out, int n) {
    int e = blockIdx.x * 256 + threadIdx.x;
    if (e >= n) return;
    float z = p[e] + p[n + e];
    out[e] = 1.0f / (1.0f + EXP2F(-LOG2E * z));
}

extern "C" void kernel_launch(void* const* d_in, const int* in_sizes, int n_in,
                              void* d_out, int out_size, void* d_ws, size_t ws_size,
                              hipStream_t stream) {
    const float* x  = (const float*)d_in[0];
    const float* w1 = (const float*)d_in[1];
    const float* s1 = (const float*)d_in[2];
    const float* w2 = (const float*)d_in[3];
    const float* s2 = (const float*)d_in[4];
    const float* w3 = (const float*)d_in[5];
    const float* s3 = (const float*)d_in[6];
    float* out = (float*)d_out;

    float* ws  = (float*)d_ws;
    float* h1  = ws;                    // 2048*256   = 524288
    float* h2  = h1  + 524288;          // 2048*128   = 262144
    float* p3  = h2  + 262144;          // 2*2048*64  = 262144
    float* T1  = p3  + 262144;          // 393216
    float* K1  = T1  + 393216;          // 32768
    float* T2  = K1  + 32768;           // 393216
    float* K2  = T2  + 393216;          // 32768
    float* T3  = K2  + 32768;           // 98304
    float* K3  = T3  + 98304;           // 8192

    prep_all<<<288, 256, 0, stream>>>(w1, s1, T1, K1, w2, s2, T2, K2, w3, s3, T3, K3);

    // L1: LEN=128, OUT=256, OCH=4, BPT=2 -> 4096 waves, 1024 blocks (16 w/CU)
    kan_pipe<128, 256, 4, 2, 1, 0><<<1024, 256, 0, stream>>>(
        x, (const char*)T1, K1, h1);
    // L2: LEN=256, OUT=128, OCH=2, BPT=2 -> 2048 waves, 512 blocks (8 w/CU)
    kan_pipe<256, 128, 2, 2, 1, 0><<<512, 256, 0, stream>>>(
        h1, (const char*)T2, K2, h2);
    // L3: LEN=64 (2 halves of 128), OUT=64, BPT=2 -> 2048 waves, 512 blocks; partials
    kan_pipe<64, 64, 1, 2, 2, 1><<<512, 256, 0, stream>>>(
        h2, (const char*)T3, K3, p3);
    // epilogue: sigmoid(p0+p1) -> out  (2048*64)
    sigmoid_combine<<<512, 256, 0, stream>>>(p3, out, 131072);
}